// Round 2
// baseline (555.505 us; speedup 1.0000x reference)
//
#include <hip/hip_runtime.h>

#define BN_TOT 8192   // B*N
#define KN 12
#define DNBR 320
#define DNEW 256

// One block per atom (b,n). 256 threads = 4 waves.
// Wave tiling of the e-GEMM (12 k x 256 d): kg = w>>1 picks k-range (6 rows),
// dh = w&1 picks d-half (128 cols). Thread holds acc[6][2] (2 consecutive d).
__global__ __launch_bounds__(256) void fused_gnn(
    const float* __restrict__ atomf,   // (BN,256)
    const float* __restrict__ nbrf,    // (BN,12,320)
    const float* __restrict__ smaskg,  // (BN,12)
    const float* __restrict__ amaskg,  // (BN,12)
    const float* __restrict__ Wa,      // (256,256)
    const float* __restrict__ ba,      // (256)
    const float* __restrict__ Wn,      // (320,256)
    const float* __restrict__ bnb,     // (256)
    const float* __restrict__ walg,    // (32)
    const float* __restrict__ balg,    // (1)
    const float* __restrict__ gam,     // (256)
    const float* __restrict__ bet,     // (256)
    float* __restrict__ out)           // (BN,256)
{
    __shared__ __align__(16) float a_nbr[KN * DNBR];  // 15360 B
    __shared__ __align__(16) float a_at[DNEW];
    __shared__ __align__(16) float h_l[DNEW];         // h = atom@Wa + ba
    __shared__ float s_lds[KN][8];                    // scores [k][head]
    __shared__ __align__(16) float ctx_lds[2][DNEW];  // per-kgroup ctx partials
    __shared__ float smask_l[KN], amask_l[KN], wal[32];
    __shared__ float red[8];

    const int atom = blockIdx.x;
    const int t = threadIdx.x;
    const int lane = t & 63;
    const int w = t >> 6;

    // ---- stage neighbor features -> LDS (3840 floats = 960 float4) ----
    const float4* nb4 = (const float4*)(nbrf + (size_t)atom * (KN * DNBR));
    for (int i = t; i < KN * DNBR / 4; i += 256) {
        ((float4*)a_nbr)[i] = nb4[i];
    }
    // ---- stage atom feature (256 floats = 64 float4) ----
    if (t < 64) {
        ((float4*)a_at)[t] = ((const float4*)(atomf + (size_t)atom * DNEW))[t];
    }
    if (t >= 64 && t < 64 + KN)  smask_l[t - 64] = smaskg[atom * KN + (t - 64)];
    if (t >= 96 && t < 96 + KN)  amask_l[t - 96] = amaskg[atom * KN + (t - 96)];
    if (t >= 128 && t < 160)     wal[t - 128] = walg[t - 128];
    __syncthreads();

    // ---- h phase: thread t computes h[t] = a_at . Wa[:,t] + ba[t] ----
    {
        float hacc = 0.f;
        for (int c = 0; c < DNEW; c += 4) {
            float4 a = *(const float4*)&a_at[c];
            float w0 = Wa[(c + 0) * DNEW + t];
            float w1 = Wa[(c + 1) * DNEW + t];
            float w2 = Wa[(c + 2) * DNEW + t];
            float w3 = Wa[(c + 3) * DNEW + t];
            hacc = fmaf(a.x, w0, hacc);
            hacc = fmaf(a.y, w1, hacc);
            hacc = fmaf(a.z, w2, hacc);
            hacc = fmaf(a.w, w3, hacc);
        }
        h_l[t] = hacc + ba[t];
    }
    __syncthreads();

    // ---- e-GEMM: acc[i][j] = e[k0+i][d0+j] ----
    const int kg = w >> 1;            // 0,1
    const int dh = w & 1;             // 0,1
    const int d0 = dh * 128 + lane * 2;
    const int k0 = kg * 6;

    float acc[6][2];
#pragma unroll
    for (int i = 0; i < 6; i++) { acc[i][0] = 0.f; acc[i][1] = 0.f; }

    for (int c = 0; c < DNBR; c += 4) {
        float2 w0 = *(const float2*)&Wn[(c + 0) * DNEW + d0];
        float2 w1 = *(const float2*)&Wn[(c + 1) * DNEW + d0];
        float2 w2 = *(const float2*)&Wn[(c + 2) * DNEW + d0];
        float2 w3 = *(const float2*)&Wn[(c + 3) * DNEW + d0];
#pragma unroll
        for (int i = 0; i < 6; i++) {
            float4 a = *(const float4*)&a_nbr[(k0 + i) * DNBR + c];
            acc[i][0] = fmaf(a.x, w0.x, acc[i][0]);
            acc[i][0] = fmaf(a.y, w1.x, acc[i][0]);
            acc[i][0] = fmaf(a.z, w2.x, acc[i][0]);
            acc[i][0] = fmaf(a.w, w3.x, acc[i][0]);
            acc[i][1] = fmaf(a.x, w0.y, acc[i][1]);
            acc[i][1] = fmaf(a.y, w1.y, acc[i][1]);
            acc[i][1] = fmaf(a.z, w2.y, acc[i][1]);
            acc[i][1] = fmaf(a.w, w3.y, acc[i][1]);
        }
    }
    {
        float2 bn2 = *(const float2*)&bnb[d0];
#pragma unroll
        for (int i = 0; i < 6; i++) { acc[i][0] += bn2.x; acc[i][1] += bn2.y; }
    }

    // ---- GATv2 scores: leakyrelu(h + e) . w_align, reduce 16 lanes/head ----
    const float bal = balg[0];
    const float hx = h_l[d0], hy = h_l[d0 + 1];
    const float wa0 = wal[d0 & 31], wa1 = wal[(d0 + 1) & 31];
    const int ghead = dh * 4 + (lane >> 4);   // global head 0..7
#pragma unroll
    for (int i = 0; i < 6; i++) {
        float f0 = hx + acc[i][0]; f0 = f0 > 0.f ? f0 : 0.01f * f0;
        float f1 = hy + acc[i][1]; f1 = f1 > 0.f ? f1 : 0.01f * f1;
        float p = f0 * wa0 + f1 * wa1;
        p += __shfl_xor(p, 1);
        p += __shfl_xor(p, 2);
        p += __shfl_xor(p, 4);
        p += __shfl_xor(p, 8);
        if ((lane & 15) == 0) s_lds[k0 + i][ghead] = p + bal + smask_l[k0 + i];
    }
    __syncthreads();

    // ---- softmax over K (in-register, redundant per-thread) + ctx partial ----
    float sc[KN];
    float m = -1e30f;
#pragma unroll
    for (int k = 0; k < KN; k++) { sc[k] = s_lds[k][ghead]; m = fmaxf(m, sc[k]); }
    float ssum = 0.f;
#pragma unroll
    for (int k = 0; k < KN; k++) ssum += __expf(sc[k] - m);
    const float inv = 1.f / ssum;
    float c0 = 0.f, c1 = 0.f;
#pragma unroll
    for (int i = 0; i < 6; i++) {
        float at = __expf(sc[k0 + i] - m) * inv * amask_l[k0 + i];
        c0 = fmaf(at, acc[i][0], c0);
        c1 = fmaf(at, acc[i][1], c1);
    }
    ctx_lds[kg][d0] = c0;
    ctx_lds[kg][d0 + 1] = c1;
    __syncthreads();

    // ---- LayerNorm over 256 channels ----
    float x = ctx_lds[0][t] + ctx_lds[1][t];
    float s1 = x, s2 = x * x;
#pragma unroll
    for (int off = 1; off < 64; off <<= 1) {
        s1 += __shfl_xor(s1, off);
        s2 += __shfl_xor(s2, off);
    }
    if (lane == 0) { red[w] = s1; red[4 + w] = s2; }
    __syncthreads();
    float ts1 = red[0] + red[1] + red[2] + red[3];
    float ts2 = red[4] + red[5] + red[6] + red[7];
    float mu = ts1 * (1.f / 256.f);
    float var = ts2 * (1.f / 256.f) - mu * mu;
    var = fmaxf(var, 0.f);
    float r = rsqrtf(var + 1e-5f);
    float y = (x - mu) * r * gam[t] + bet[t];
    out[(size_t)atom * DNEW + t] = y;
}

extern "C" void kernel_launch(void* const* d_in, const int* in_sizes, int n_in,
                              void* d_out, int out_size, void* d_ws, size_t ws_size,
                              hipStream_t stream) {
    const float* atomf = (const float*)d_in[0];
    const float* nbrf  = (const float*)d_in[1];
    const float* smask = (const float*)d_in[2];
    const float* amask = (const float*)d_in[3];
    const float* Wa    = (const float*)d_in[4];
    const float* ba    = (const float*)d_in[5];
    const float* Wn    = (const float*)d_in[6];
    const float* bnb   = (const float*)d_in[7];
    const float* wal   = (const float*)d_in[8];
    const float* bal   = (const float*)d_in[9];
    const float* gam   = (const float*)d_in[10];
    const float* bet   = (const float*)d_in[11];
    float* out = (float*)d_out;

    fused_gnn<<<BN_TOT, 256, 0, stream>>>(atomf, nbrf, smask, amask, Wa, ba,
                                          Wn, bnb, wal, bal, gam, bet, out);
}

// Round 3
// 323.615 us; speedup vs baseline: 1.7166x; 1.7166x over previous
//
#include <hip/hip_runtime.h>

#define KN 12
#define DNBR 320
#define DNEW 256
#define BN_TOT 8192

typedef short bf8_t __attribute__((ext_vector_type(8)));   // 8 bf16 (4 VGPRs)
typedef float f32x4 __attribute__((ext_vector_type(4)));
using u16 = unsigned short;
using u32 = unsigned int;

__device__ __forceinline__ u16 f2bf(float f) {
    u32 x = __float_as_uint(f);
    return (u16)((x + 0x7fffu + ((x >> 16) & 1u)) >> 16);  // RNE
}

// ws layout:
//   WnT bf16 [256 n][320 k] : offset 0        (163840 B)
//   WaT bf16 [256 n][256 k] : offset 163840   (131072 B)
//   hbuf f32 [8192][256]    : offset 294912   (8388608 B)
#define WS_WNT 0
#define WS_WAT 163840
#define WS_H   294912

// ---- kernel 1: convert + transpose weights to bf16 ----
__global__ __launch_bounds__(256) void convert_weights(
    const float* __restrict__ Wn, const float* __restrict__ Wa,
    u16* __restrict__ WnT, u16* __restrict__ WaT)
{
    int t = blockIdx.x * 256 + threadIdx.x;
    int stride = gridDim.x * 256;
    for (int i = t; i < 256 * 320; i += stride) {
        int n = i / 320, k = i - n * 320;
        WnT[i] = f2bf(Wn[k * 256 + n]);
    }
    for (int i = t; i < 256 * 256; i += stride) {
        int n = i >> 8, k = i & 255;
        WaT[i] = f2bf(Wa[k * 256 + n]);
    }
}

// ---- kernel 2: h = atom @ Wa + ba, MFMA, 64 atoms per block ----
__global__ __launch_bounds__(256) void h_gemm(
    const float* __restrict__ atomf, const u16* __restrict__ WaT,
    const float* __restrict__ ba, float* __restrict__ hbuf)
{
    __shared__ u16 A[64 * 264];   // stride 264 bf16 (=132 dwords, %32=4: 2-way max)
    const int t = threadIdx.x, l = t & 63, w = t >> 6;
    const int blk = blockIdx.x;

    const float4* src = (const float4*)(atomf + (size_t)blk * 64 * 256);
    for (int i = t; i < 64 * 64; i += 256) {
        float4 v = src[i];
        int row = i >> 6, c4 = (i & 63) << 2;
        u16 tmp[4] = { f2bf(v.x), f2bf(v.y), f2bf(v.z), f2bf(v.w) };
        *(ushort4*)&A[row * 264 + c4] = *(ushort4*)tmp;
    }
    __syncthreads();

    const int m = l & 15, q = l >> 4;
    bf8_t afr[8];
#pragma unroll
    for (int ks = 0; ks < 8; ks++)
        afr[ks] = *(bf8_t*)&A[(w * 16 + m) * 264 + ks * 32 + q * 8];

    for (int nt = 0; nt < 16; nt++) {
        const int col = nt * 16 + m;
        f32x4 acc = {0.f, 0.f, 0.f, 0.f};
#pragma unroll
        for (int ks = 0; ks < 8; ks++) {
            bf8_t bfr = *(const bf8_t*)&WaT[col * 256 + ks * 32 + q * 8];
            acc = __builtin_amdgcn_mfma_f32_16x16x32_bf16(afr[ks], bfr, acc, 0, 0, 0);
        }
        float bav = ba[col];
#pragma unroll
        for (int r = 0; r < 4; r++) {
            int row = blk * 64 + w * 16 + q * 4 + r;
            hbuf[(size_t)row * 256 + col] = acc[r] + bav;
        }
    }
}

// ---- kernel 3: fused e-GEMM + GATv2 + softmax + ctx + LN, 2 atoms/block ----
__global__ __launch_bounds__(256) void fused_attn(
    const float* __restrict__ nbrf, const float* __restrict__ smaskg,
    const float* __restrict__ amaskg, const u16* __restrict__ WnT,
    const float* __restrict__ bnb, const float* __restrict__ walg,
    const float* __restrict__ balg, const float* __restrict__ gam,
    const float* __restrict__ bet, const float* __restrict__ hbuf,
    float* __restrict__ out)
{
    __shared__ union {
        u16 A[2][16 * 328];      // stride 328 bf16 (=164 dwords, %32=4)
        float e[2][12][256];     // 24576 B (A dead once MFMA done)
    } U;
    __shared__ float h_l[2][256];
    __shared__ float s_l[2][12][8];
    __shared__ float smask_l[2][12], amask_l[2][12], wal_l[32];
    __shared__ float red_l[2][8];

    const int t = threadIdx.x, l = t & 63, w = t >> 6;
    const int a0 = blockIdx.x * 2;

    // stage nbr (2 atoms x 12 x 320 f32) -> bf16 LDS
    const float4* nb4 = (const float4*)(nbrf + (size_t)a0 * KN * DNBR);
    for (int i = t; i < 1920; i += 256) {
        float4 v = nb4[i];
        int at = i / 960, rem = i - at * 960;
        int row = rem / 80, c4 = (rem - row * 80) * 4;
        u16 tmp[4] = { f2bf(v.x), f2bf(v.y), f2bf(v.z), f2bf(v.w) };
        *(ushort4*)&U.A[at][row * 328 + c4] = *(ushort4*)tmp;
    }
    // zero-pad rows 12..15 (2 at x 4 rows x 82 ushort4)
    for (int i = t; i < 656; i += 256) {
        int at = i / 328, rem = i - at * 328;
        int row = 12 + rem / 82, c4 = (rem % 82) * 4;
        ushort4 z = {0, 0, 0, 0};
        *(ushort4*)&U.A[at][row * 328 + c4] = z;
    }
    if (t < 128) {
        int at = t >> 6, c4 = (t & 63) << 2;
        *(float4*)&h_l[at][c4] = *(const float4*)&hbuf[(size_t)(a0 + at) * 256 + c4];
    } else if (t < 152) {
        int i = t - 128;
        smask_l[i / 12][i % 12] = smaskg[a0 * KN + i];
    } else if (t < 176) {
        int i = t - 152;
        amask_l[i / 12][i % 12] = amaskg[a0 * KN + i];
    } else if (t < 208) {
        wal_l[t - 176] = walg[t - 176];
    }
    __syncthreads();

    // e-GEMM: 2 M-tiles (atoms) x 4 N-tiles per wave, K = 10 x 32
    const int m = l & 15, q = l >> 4;
    f32x4 acc[2][4];
#pragma unroll
    for (int at = 0; at < 2; at++)
#pragma unroll
        for (int j = 0; j < 4; j++) acc[at][j] = (f32x4){0.f, 0.f, 0.f, 0.f};

    for (int ks = 0; ks < 10; ks++) {
        bf8_t af0 = *(bf8_t*)&U.A[0][m * 328 + ks * 32 + q * 8];
        bf8_t af1 = *(bf8_t*)&U.A[1][m * 328 + ks * 32 + q * 8];
        bf8_t bfr[4];
#pragma unroll
        for (int j = 0; j < 4; j++) {
            int col = w * 64 + j * 16 + m;
            bfr[j] = *(const bf8_t*)&WnT[col * 320 + ks * 32 + q * 8];
        }
#pragma unroll
        for (int j = 0; j < 4; j++) {
            acc[0][j] = __builtin_amdgcn_mfma_f32_16x16x32_bf16(af0, bfr[j], acc[0][j], 0, 0, 0);
            acc[1][j] = __builtin_amdgcn_mfma_f32_16x16x32_bf16(af1, bfr[j], acc[1][j], 0, 0, 0);
        }
    }
    __syncthreads();   // all waves done reading A before union reuse

    // dump e = acc + bnb to LDS (C layout: col=lane&15, row=q*4+r)
#pragma unroll
    for (int at = 0; at < 2; at++)
#pragma unroll
        for (int j = 0; j < 4; j++) {
            int col = w * 64 + j * 16 + m;
            float bv = bnb[col];
#pragma unroll
            for (int r = 0; r < 4; r++) {
                int row = q * 4 + r;
                if (row < 12) U.e[at][row][col] = acc[at][j][r] + bv;
            }
        }
    __syncthreads();

    // GATv2 scores: leakyrelu(h + e) . w_align per head, 32-lane shuffle reduce
    const float bal = balg[0];
    const int hd = t >> 5, d = t & 31;
    const float wv = wal_l[d];
#pragma unroll
    for (int at = 0; at < 2; at++) {
        const float hv = h_l[at][hd * 32 + d];
#pragma unroll
        for (int k = 0; k < 12; k++) {
            float f = hv + U.e[at][k][hd * 32 + d];
            f = f > 0.f ? f : 0.01f * f;
            float p = f * wv;
            p += __shfl_xor(p, 1);
            p += __shfl_xor(p, 2);
            p += __shfl_xor(p, 4);
            p += __shfl_xor(p, 8);
            p += __shfl_xor(p, 16);
            if (d == 0) s_l[at][k][hd] = p + bal + smask_l[at][k];
        }
    }
    __syncthreads();

    // softmax over K (redundant per-thread) + ctx (thread t = channel t)
    float x[2];
#pragma unroll
    for (int at = 0; at < 2; at++) {
        float sc[12], mx = -1e30f;
#pragma unroll
        for (int k = 0; k < 12; k++) { sc[k] = s_l[at][k][hd]; mx = fmaxf(mx, sc[k]); }
        float ss = 0.f;
#pragma unroll
        for (int k = 0; k < 12; k++) { sc[k] = __expf(sc[k] - mx); ss += sc[k]; }
        float inv = 1.f / ss;
        float c = 0.f;
#pragma unroll
        for (int k = 0; k < 12; k++)
            c += sc[k] * inv * amask_l[at][k] * U.e[at][k][t];
        x[at] = c;
    }

    // LayerNorm over 256 channels, both atoms
    float s1a = x[0], s2a = x[0] * x[0];
    float s1b = x[1], s2b = x[1] * x[1];
#pragma unroll
    for (int off = 1; off < 64; off <<= 1) {
        s1a += __shfl_xor(s1a, off);
        s2a += __shfl_xor(s2a, off);
        s1b += __shfl_xor(s1b, off);
        s2b += __shfl_xor(s2b, off);
    }
    if (l == 0) {
        red_l[0][w] = s1a; red_l[0][4 + w] = s2a;
        red_l[1][w] = s1b; red_l[1][4 + w] = s2b;
    }
    __syncthreads();
#pragma unroll
    for (int at = 0; at < 2; at++) {
        float ts1 = red_l[at][0] + red_l[at][1] + red_l[at][2] + red_l[at][3];
        float ts2 = red_l[at][4] + red_l[at][5] + red_l[at][6] + red_l[at][7];
        float mu = ts1 * (1.f / 256.f);
        float var = ts2 * (1.f / 256.f) - mu * mu;
        var = fmaxf(var, 0.f);
        float r = rsqrtf(var + 1e-5f);
        out[(size_t)(a0 + at) * 256 + t] = (x[at] - mu) * r * gam[t] + bet[t];
    }
}

extern "C" void kernel_launch(void* const* d_in, const int* in_sizes, int n_in,
                              void* d_out, int out_size, void* d_ws, size_t ws_size,
                              hipStream_t stream) {
    const float* atomf = (const float*)d_in[0];
    const float* nbrf  = (const float*)d_in[1];
    const float* smask = (const float*)d_in[2];
    const float* amask = (const float*)d_in[3];
    const float* Wa    = (const float*)d_in[4];
    const float* ba    = (const float*)d_in[5];
    const float* Wn    = (const float*)d_in[6];
    const float* bnb   = (const float*)d_in[7];
    const float* wal   = (const float*)d_in[8];
    const float* bal   = (const float*)d_in[9];
    const float* gam   = (const float*)d_in[10];
    const float* bet   = (const float*)d_in[11];
    float* outp = (float*)d_out;

    u16* WnT   = (u16*)((char*)d_ws + WS_WNT);
    u16* WaT   = (u16*)((char*)d_ws + WS_WAT);
    float* hbuf = (float*)((char*)d_ws + WS_H);

    convert_weights<<<64, 256, 0, stream>>>(Wn, Wa, WnT, WaT);
    h_gemm<<<BN_TOT / 64, 256, 0, stream>>>(atomf, WaT, ba, hbuf);
    fused_attn<<<BN_TOT / 2, 256, 0, stream>>>(nbrf, smask, amask, WnT, bnb,
                                               wal, bal, gam, bet, hbuf, outp);
}

// Round 4
// 291.451 us; speedup vs baseline: 1.9060x; 1.1104x over previous
//
#include <hip/hip_runtime.h>

#define KN 12
#define DNBR 320
#define DNEW 256
#define BN_TOT 8192
#define ATB 4                 // atoms per block
#define KTOT 576              // 320 (Wn) + 256 (Wa)
#define NKS 18                // 576/32
#define AROWS 55              // 4 atoms * 13 rows + 3 zero pad rows
#define ASTR 584              // row stride in u16 (576 + 8 pad; dword%32==4 -> 2-way max)

typedef short bf8_t __attribute__((ext_vector_type(8)));
typedef float f32x4 __attribute__((ext_vector_type(4)));
typedef unsigned short us8 __attribute__((ext_vector_type(8)));
using u16 = unsigned short;
using u32 = unsigned int;

__device__ __forceinline__ u16 f2bf(float f) {
    u32 x = __float_as_uint(f);
    return (u16)((x + 0x7fffu + ((x >> 16) & 1u)) >> 16);  // RNE
}

__device__ __forceinline__ us8 pack8(float4 a, float4 b) {
    us8 v;
    v[0] = f2bf(a.x); v[1] = f2bf(a.y); v[2] = f2bf(a.z); v[3] = f2bf(a.w);
    v[4] = f2bf(b.x); v[5] = f2bf(b.y); v[6] = f2bf(b.z); v[7] = f2bf(b.w);
    return v;
}

// ---- kernel 1: build fragment-major stacked B2 = [[Wn],[Wa]] (576x256 bf16) ----
// B2 tile (ks,nt): 64 lanes x 8 u16 contiguous; lane l=q*16+m holds
// k = ks*32+q*8+e, col = nt*16+m.  One wave-load = 1KB fully coalesced.
__global__ __launch_bounds__(256) void build_b2(
    const float* __restrict__ Wn, const float* __restrict__ Wa,
    u16* __restrict__ B2)
{
    int tile = blockIdx.x * 4 + (threadIdx.x >> 6);   // 0..287 = ks*16+nt
    int l = threadIdx.x & 63;
    int ks = tile >> 4, nt = tile & 15;
    int q = l >> 4, m = l & 15;
    int col = nt * 16 + m;
    us8 v;
#pragma unroll
    for (int e = 0; e < 8; e++) {
        int k = ks * 32 + q * 8 + e;
        float f = (k < DNBR) ? Wn[k * DNEW + col] : Wa[(k - DNBR) * DNEW + col];
        v[e] = f2bf(f);
    }
    *(us8*)&B2[(size_t)tile * 512 + l * 8] = v;
}

// ---- kernel 2: fully fused. 4 atoms/block, A rows = [nbr_k | atom] (k=0..11),
// row12 = [0 | atom] (gives h), C = h+e in regs; epilogue register-resident. ----
__global__ __launch_bounds__(256) void fused_all(
    const float* __restrict__ atomf, const float* __restrict__ nbrf,
    const float* __restrict__ smaskg, const float* __restrict__ amaskg,
    const float* __restrict__ ba, const u16* __restrict__ B2,
    const float* __restrict__ bnb, const float* __restrict__ walg,
    const float* __restrict__ balg, const float* __restrict__ gam,
    const float* __restrict__ bet, float* __restrict__ out)
{
    __shared__ u16 A[AROWS * ASTR];          // 64240 B
    __shared__ float ctx_l[ATB][256];        // 4096 B
    __shared__ float s_l[ATB][8][12];        // 1536 B
    __shared__ float attnm_l[ATB][8][16];    // 2048 B
    __shared__ float bias2_l[256], bnb_l[256], wal_l[32];
    __shared__ float smask_l[ATB * 12], amask_l[ATB * 12];
    __shared__ float red_l[ATB][8];

    const int t = threadIdx.x;
    const int l = t & 63, w = t >> 6, q = l >> 4, m = l & 15;
    const int a0 = blockIdx.x * ATB;

    // ---- stage params ----
    bias2_l[t] = bnb[t] + ba[t];
    bnb_l[t] = bnb[t];
    if (t < 32) wal_l[t] = walg[t];
    if (t < 48) smask_l[t] = smaskg[(size_t)a0 * KN + t];
    if (t >= 64 && t < 112) amask_l[t - 64] = amaskg[(size_t)a0 * KN + (t - 64)];

    // ---- stage A: 55 rows x 72 16B-chunks ----
    for (int idx = t; idx < AROWS * 72; idx += 256) {
        int R = idx / 72, c8 = idx - R * 72;
        int k0 = c8 * 8;
        us8 v = {0, 0, 0, 0, 0, 0, 0, 0};
        if (R < 52) {
            int at = R / 13, row = R - at * 13;
            const float* src = nullptr;
            if (row < 12) {
                if (k0 < DNBR) src = nbrf + ((size_t)(a0 + at) * KN + row) * DNBR + k0;
                else           src = atomf + (size_t)(a0 + at) * DNEW + (k0 - DNBR);
            } else if (k0 >= DNBR) {
                src = atomf + (size_t)(a0 + at) * DNEW + (k0 - DNBR);
            }
            if (src) v = pack8(*(const float4*)src, *(const float4*)(src + 4));
        }
        *(us8*)&A[R * ASTR + k0] = v;
    }
    __syncthreads();

    // ---- GEMM: C[at][row q*4+r][col w*64+j*16+m] = (h+e)_acc ----
    f32x4 acc[ATB][4];
#pragma unroll
    for (int at = 0; at < ATB; at++)
#pragma unroll
        for (int j = 0; j < 4; j++) acc[at][j] = (f32x4){0.f, 0.f, 0.f, 0.f};

    for (int ks = 0; ks < NKS; ks++) {
        bf8_t af[ATB], bf[4];
#pragma unroll
        for (int at = 0; at < ATB; at++)
            af[at] = *(bf8_t*)&A[(at * 13 + m) * ASTR + ks * 32 + q * 8];
#pragma unroll
        for (int j = 0; j < 4; j++)
            bf[j] = *(const bf8_t*)&B2[((size_t)(ks * 16 + w * 4 + j) * 64 + l) * 8];
#pragma unroll
        for (int at = 0; at < ATB; at++)
#pragma unroll
            for (int j = 0; j < 4; j++)
                acc[at][j] = __builtin_amdgcn_mfma_f32_16x16x32_bf16(af[at], bf[j], acc[at][j], 0, 0, 0);
    }

    // ---- GATv2 scores from registers: score(k,head) done within one wave ----
    const float bal = balg[0];
    float b2v[4], wv[4];
#pragma unroll
    for (int j = 0; j < 4; j++) {
        b2v[j] = bias2_l[w * 64 + j * 16 + m];
        wv[j] = wal_l[(j * 16 + m) & 31];
    }
#pragma unroll
    for (int at = 0; at < ATB; at++) {
#pragma unroll
        for (int jj = 0; jj < 2; jj++) {
#pragma unroll
            for (int r = 0; r < 4; r++) {
                float p = 0.f;
#pragma unroll
                for (int jo = 0; jo < 2; jo++) {
                    int j = jj * 2 + jo;
                    float f = acc[at][j][r] + b2v[j];
                    f = f > 0.f ? f : 0.01f * f;
                    p = fmaf(f, wv[j], p);
                }
                p += __shfl_xor(p, 1);
                p += __shfl_xor(p, 2);
                p += __shfl_xor(p, 4);
                p += __shfl_xor(p, 8);
                int k = q * 4 + r;
                if (m == 0 && k < 12)
                    s_l[at][w * 2 + jj][k] = p + bal + smask_l[at * 12 + k];
            }
        }
    }
    __syncthreads();

    // ---- softmax over K per (atom, head); row-12 weight = -sA (h subtraction) ----
    if (t < 32) {
        int at = t >> 3, hd = t & 7;
        float sc[12], mx = -1e30f;
#pragma unroll
        for (int k = 0; k < 12; k++) { sc[k] = s_l[at][hd][k]; mx = fmaxf(mx, sc[k]); }
        float ss = 0.f;
#pragma unroll
        for (int k = 0; k < 12; k++) { sc[k] = __expf(sc[k] - mx); ss += sc[k]; }
        float inv = 1.f / ss;
        float sA = 0.f;
#pragma unroll
        for (int k = 0; k < 12; k++) {
            float a_ = sc[k] * inv * amask_l[at * 12 + k];
            attnm_l[at][hd][k] = a_;
            sA += a_;
        }
        attnm_l[at][hd][12] = -sA;
        attnm_l[at][hd][13] = 0.f;
        attnm_l[at][hd][14] = 0.f;
        attnm_l[at][hd][15] = 0.f;
    }
    __syncthreads();

    // ---- ctx[col] = sum_k attnm_k*acc_k + sA*bnb[col], reduce over q-groups ----
#pragma unroll
    for (int at = 0; at < ATB; at++) {
#pragma unroll
        for (int j = 0; j < 4; j++) {
            int hd = w * 2 + (j >> 1);
            f32x4 am = *(f32x4*)&attnm_l[at][hd][q * 4];
            float cp = am[0] * acc[at][j][0] + am[1] * acc[at][j][1] +
                       am[2] * acc[at][j][2] + am[3] * acc[at][j][3];
            cp += __shfl_xor(cp, 16);
            cp += __shfl_xor(cp, 32);
            float sA = -attnm_l[at][hd][12];
            float cv = cp + sA * bnb_l[w * 64 + j * 16 + m];
            if (q == 0) ctx_l[at][w * 64 + j * 16 + m] = cv;
        }
    }
    __syncthreads();

    // ---- LayerNorm over 256 channels, 4 atoms ----
    float x[ATB];
#pragma unroll
    for (int at = 0; at < ATB; at++) {
        x[at] = ctx_l[at][t];
        float s1 = x[at], s2 = x[at] * x[at];
#pragma unroll
        for (int off = 1; off < 64; off <<= 1) {
            s1 += __shfl_xor(s1, off);
            s2 += __shfl_xor(s2, off);
        }
        if (l == 0) { red_l[at][w] = s1; red_l[at][4 + w] = s2; }
    }
    __syncthreads();
#pragma unroll
    for (int at = 0; at < ATB; at++) {
        float ts1 = red_l[at][0] + red_l[at][1] + red_l[at][2] + red_l[at][3];
        float ts2 = red_l[at][4] + red_l[at][5] + red_l[at][6] + red_l[at][7];
        float mu = ts1 * (1.f / 256.f);
        float var = ts2 * (1.f / 256.f) - mu * mu;
        var = fmaxf(var, 0.f);
        float r = rsqrtf(var + 1e-5f);
        out[(size_t)(a0 + at) * DNEW + t] = (x[at] - mu) * r * gam[t] + bet[t];
    }
}

extern "C" void kernel_launch(void* const* d_in, const int* in_sizes, int n_in,
                              void* d_out, int out_size, void* d_ws, size_t ws_size,
                              hipStream_t stream) {
    const float* atomf = (const float*)d_in[0];
    const float* nbrf  = (const float*)d_in[1];
    const float* smask = (const float*)d_in[2];
    const float* amask = (const float*)d_in[3];
    const float* Wa    = (const float*)d_in[4];
    const float* ba    = (const float*)d_in[5];
    const float* Wn    = (const float*)d_in[6];
    const float* bnb   = (const float*)d_in[7];
    const float* wal   = (const float*)d_in[8];
    const float* bal   = (const float*)d_in[9];
    const float* gam   = (const float*)d_in[10];
    const float* bet   = (const float*)d_in[11];
    float* outp = (float*)d_out;

    u16* B2 = (u16*)d_ws;   // 294912 B

    build_b2<<<72, 256, 0, stream>>>(Wn, Wa, B2);
    fused_all<<<BN_TOT / ATB, 256, 0, stream>>>(atomf, nbrf, smask, amask, ba,
                                                B2, bnb, wal, bal, gam, bet, outp);
}

// Round 6
// 268.047 us; speedup vs baseline: 2.0724x; 1.0873x over previous
//
#include <hip/hip_runtime.h>

#define KN 12
#define DNBR 320
#define DNEW 256
#define BN_TOT 8192
#define ATB 2                 // atoms per block
#define NKS_E 10              // 320/32
#define NKS_H 8               // 256/32
#define ASTR_E 328            // A_e row stride in u16 (320 + 8 pad)
#define ASTR_H 264            // A_h row stride in u16 (256 + 8 pad)

typedef short bf8_t __attribute__((ext_vector_type(8)));
typedef float f32x4 __attribute__((ext_vector_type(4)));
typedef unsigned short us8 __attribute__((ext_vector_type(8)));
using u16 = unsigned short;
using u32 = unsigned int;

__device__ __forceinline__ u16 f2bf(float f) {
    u32 x = __float_as_uint(f);
    return (u16)((x + 0x7fffu + ((x >> 16) & 1u)) >> 16);  // RNE
}

__device__ __forceinline__ us8 pack8(float4 a, float4 b) {
    us8 v;
    v[0] = f2bf(a.x); v[1] = f2bf(a.y); v[2] = f2bf(a.z); v[3] = f2bf(a.w);
    v[4] = f2bf(b.x); v[5] = f2bf(b.y); v[6] = f2bf(b.z); v[7] = f2bf(b.w);
    return v;
}

// ---- kernel 1: fragment-major stacked B2: tiles 0..159 = Wn (10 ks x 16 nt),
// tiles 160..287 = Wa (8 ks x 16 nt). Tile = 64 lanes x 8 u16 (1KB). ----
__global__ __launch_bounds__(256) void build_b2(
    const float* __restrict__ Wn, const float* __restrict__ Wa,
    u16* __restrict__ B2)
{
    int tile = blockIdx.x * 4 + (threadIdx.x >> 6);   // 0..287
    int l = threadIdx.x & 63;
    int q = l >> 4, m = l & 15;
    us8 v;
    if (tile < 160) {
        int ks = tile >> 4, nt = tile & 15;
        int col = nt * 16 + m;
#pragma unroll
        for (int e = 0; e < 8; e++)
            v[e] = f2bf(Wn[(ks * 32 + q * 8 + e) * DNEW + col]);
    } else {
        int tt = tile - 160;
        int ks = tt >> 4, nt = tt & 15;
        int col = nt * 16 + m;
#pragma unroll
        for (int e = 0; e < 8; e++)
            v[e] = f2bf(Wa[(ks * 32 + q * 8 + e) * DNEW + col]);
    }
    *(us8*)&B2[(size_t)tile * 512 + l * 8] = v;
}

// ---- kernel 2: fused. 2 atoms/block, split e-GEMM (K=320) + h-GEMM (K=256). ----
__global__ __launch_bounds__(256, 4) void fused_all(
    const float* __restrict__ atomf, const float* __restrict__ nbrf,
    const float* __restrict__ smaskg, const float* __restrict__ amaskg,
    const float* __restrict__ ba, const u16* __restrict__ B2,
    const float* __restrict__ bnb, const float* __restrict__ walg,
    const float* __restrict__ balg, const float* __restrict__ gam,
    const float* __restrict__ bet, float* __restrict__ out)
{
    __shared__ u16 A_e[32 * ASTR_E];        // 20992 B: 2 tiles of 16 rows
    __shared__ u16 A_h[16 * ASTR_H];        // 8448 B: rows 0,1 = atoms
    __shared__ float h_l[ATB][256];         // 2048 B
    __shared__ float ctx_l[ATB][256];       // 2048 B
    __shared__ float s_l[ATB][8][12];       // 768 B
    __shared__ float attnm_l[ATB][8][16];   // 1024 B
    __shared__ float bnb_l[256], ba_l[256], wal_l[32];
    __shared__ float smask_l[ATB * 12], amask_l[ATB * 12];
    __shared__ float red_l[ATB][8];

    const int t = threadIdx.x;
    const int l = t & 63, w = t >> 6, q = l >> 4, m = l & 15;
    const int a0 = blockIdx.x * ATB;

    // ---- params ----
    bnb_l[t] = bnb[t];
    ba_l[t] = ba[t];
    if (t < 32) wal_l[t] = walg[t];
    else if (t >= 32 && t < 56) smask_l[t - 32] = smaskg[(size_t)a0 * KN + (t - 32)];
    else if (t >= 64 && t < 88) amask_l[t - 64] = amaskg[(size_t)a0 * KN + (t - 64)];

    // ---- stage nbr -> A_e rows 0..11 (960 us8 chunks: 2 at x 12 rows x 40) ----
    const float* nbase = nbrf + (size_t)a0 * (KN * DNBR);
    for (int i = t; i < 960; i += 256) {
        float4 v0 = *(const float4*)(nbase + i * 8);
        float4 v1 = *(const float4*)(nbase + i * 8 + 4);
        int at = i / 480, rem = i - at * 480;
        int row = rem / 40, c8 = rem - row * 40;
        *(us8*)&A_e[(at * 16 + row) * ASTR_E + c8 * 8] = pack8(v0, v1);
    }
    // ---- zero A_e rows 12..15 (2 at x 4 rows x 41 chunks) ----
    for (int i = t; i < 328; i += 256) {
        int at = i / 164, rem = i - at * 164;
        int rr = rem / 41, c8 = rem - rr * 41;
        us8 z = {0, 0, 0, 0, 0, 0, 0, 0};
        *(us8*)&A_e[(at * 16 + 12 + rr) * ASTR_E + c8 * 8] = z;
    }
    // ---- stage atoms -> A_h rows 0,1 ----
    if (t < 64) {
        int at = t >> 5, c8 = t & 31;
        const float* s = atomf + (size_t)(a0 + at) * DNEW + c8 * 8;
        *(us8*)&A_h[at * ASTR_H + c8 * 8] = pack8(*(const float4*)s, *(const float4*)(s + 4));
    }
    // ---- zero A_h rows 2..15 (14 x 33 chunks) ----
    for (int i = t; i < 462; i += 256) {
        int rr = i / 33, c8 = i - rr * 33;
        us8 z = {0, 0, 0, 0, 0, 0, 0, 0};
        *(us8*)&A_h[(2 + rr) * ASTR_H + c8 * 8] = z;
    }
    __syncthreads();

    // ---- e-GEMM: acc_e[at][j] over cols w*64+j*16+m, rows q*4+r ----
    f32x4 acc_e[ATB][4];
    f32x4 acc_h[4];
#pragma unroll
    for (int at = 0; at < ATB; at++)
#pragma unroll
        for (int j = 0; j < 4; j++) acc_e[at][j] = (f32x4){0.f, 0.f, 0.f, 0.f};
#pragma unroll
    for (int j = 0; j < 4; j++) acc_h[j] = (f32x4){0.f, 0.f, 0.f, 0.f};

    for (int ks = 0; ks < NKS_E; ks++) {
        bf8_t af0 = *(bf8_t*)&A_e[(0 * 16 + m) * ASTR_E + ks * 32 + q * 8];
        bf8_t af1 = *(bf8_t*)&A_e[(1 * 16 + m) * ASTR_E + ks * 32 + q * 8];
        bf8_t bf[4];
#pragma unroll
        for (int j = 0; j < 4; j++)
            bf[j] = *(const bf8_t*)&B2[((size_t)(ks * 16 + w * 4 + j) * 64 + l) * 8];
#pragma unroll
        for (int j = 0; j < 4; j++) {
            acc_e[0][j] = __builtin_amdgcn_mfma_f32_16x16x32_bf16(af0, bf[j], acc_e[0][j], 0, 0, 0);
            acc_e[1][j] = __builtin_amdgcn_mfma_f32_16x16x32_bf16(af1, bf[j], acc_e[1][j], 0, 0, 0);
        }
    }
    // ---- h-GEMM: rows 0,1 = atoms ----
    for (int ks = 0; ks < NKS_H; ks++) {
        bf8_t af = *(bf8_t*)&A_h[m * ASTR_H + ks * 32 + q * 8];
#pragma unroll
        for (int j = 0; j < 4; j++) {
            bf8_t bfj = *(const bf8_t*)&B2[((size_t)(160 + ks * 16 + w * 4 + j) * 64 + l) * 8];
            acc_h[j] = __builtin_amdgcn_mfma_f32_16x16x32_bf16(af, bfj, acc_h[j], 0, 0, 0);
        }
    }
    // write h (+ba) to LDS: reg r = atom index (rows 0,1 live in q==0 lanes)
    if (q == 0) {
#pragma unroll
        for (int j = 0; j < 4; j++) {
            int col = w * 64 + j * 16 + m;
            h_l[0][col] = acc_h[j][0] + ba_l[col];
            h_l[1][col] = acc_h[j][1] + ba_l[col];
        }
    }
    __syncthreads();

    // ---- e_reg = acc_e + bnb (true e) ----
#pragma unroll
    for (int j = 0; j < 4; j++) {
        float bv = bnb_l[w * 64 + j * 16 + m];
#pragma unroll
        for (int at = 0; at < ATB; at++)
#pragma unroll
            for (int r = 0; r < 4; r++) acc_e[at][j][r] += bv;
    }

    // ---- GATv2 scores: leaky(e + h) . w_align, 16-lane shuffle reduce ----
    const float bal = balg[0];
    float hv[ATB][4], wv[4];
#pragma unroll
    for (int j = 0; j < 4; j++) {
        wv[j] = wal_l[(j * 16 + m) & 31];
#pragma unroll
        for (int at = 0; at < ATB; at++) hv[at][j] = h_l[at][w * 64 + j * 16 + m];
    }
#pragma unroll
    for (int at = 0; at < ATB; at++) {
#pragma unroll
        for (int jj = 0; jj < 2; jj++) {
#pragma unroll
            for (int r = 0; r < 4; r++) {
                float p = 0.f;
#pragma unroll
                for (int jo = 0; jo < 2; jo++) {
                    int j = jj * 2 + jo;
                    float f = acc_e[at][j][r] + hv[at][j];
                    f = f > 0.f ? f : 0.01f * f;
                    p = fmaf(f, wv[j], p);
                }
                p += __shfl_xor(p, 1);
                p += __shfl_xor(p, 2);
                p += __shfl_xor(p, 4);
                p += __shfl_xor(p, 8);
                int k = q * 4 + r;
                if (m == 0 && k < 12)
                    s_l[at][w * 2 + jj][k] = p + bal + smask_l[at * 12 + k];
            }
        }
    }
    __syncthreads();

    // ---- softmax over K per (atom, head) ----
    if (t < ATB * 8) {
        int at = t >> 3, hd = t & 7;
        float sc[12], mx = -1e30f;
#pragma unroll
        for (int k = 0; k < 12; k++) { sc[k] = s_l[at][hd][k]; mx = fmaxf(mx, sc[k]); }
        float ss = 0.f;
#pragma unroll
        for (int k = 0; k < 12; k++) { sc[k] = __expf(sc[k] - mx); ss += sc[k]; }
        float inv = 1.f / ss;
#pragma unroll
        for (int k = 0; k < 12; k++)
            attnm_l[at][hd][k] = sc[k] * inv * amask_l[at * 12 + k];
        attnm_l[at][hd][12] = 0.f;
        attnm_l[at][hd][13] = 0.f;
        attnm_l[at][hd][14] = 0.f;
        attnm_l[at][hd][15] = 0.f;
    }
    __syncthreads();

    // ---- ctx[col] = sum_k attn_k * e_k, reduce over q-groups ----
#pragma unroll
    for (int at = 0; at < ATB; at++) {
#pragma unroll
        for (int j = 0; j < 4; j++) {
            int hd = w * 2 + (j >> 1);
            f32x4 am = *(f32x4*)&attnm_l[at][hd][q * 4];
            float cp = am[0] * acc_e[at][j][0] + am[1] * acc_e[at][j][1] +
                       am[2] * acc_e[at][j][2] + am[3] * acc_e[at][j][3];
            cp += __shfl_xor(cp, 16);
            cp += __shfl_xor(cp, 32);
            if (q == 0) ctx_l[at][w * 64 + j * 16 + m] = cp;
        }
    }
    __syncthreads();

    // ---- LayerNorm over 256 channels ----
    float x[ATB];
#pragma unroll
    for (int at = 0; at < ATB; at++) {
        x[at] = ctx_l[at][t];
        float s1 = x[at], s2 = x[at] * x[at];
#pragma unroll
        for (int off = 1; off < 64; off <<= 1) {
            s1 += __shfl_xor(s1, off);
            s2 += __shfl_xor(s2, off);
        }
        if (l == 0) { red_l[at][w] = s1; red_l[at][4 + w] = s2; }
    }
    __syncthreads();
#pragma unroll
    for (int at = 0; at < ATB; at++) {
        float ts1 = red_l[at][0] + red_l[at][1] + red_l[at][2] + red_l[at][3];
        float ts2 = red_l[at][4] + red_l[at][5] + red_l[at][6] + red_l[at][7];
        float mu = ts1 * (1.f / 256.f);
        float var = ts2 * (1.f / 256.f) - mu * mu;
        var = fmaxf(var, 0.f);
        float r = rsqrtf(var + 1e-5f);
        out[(size_t)(a0 + at) * DNEW + t] = (x[at] - mu) * r * gam[t] + bet[t];
    }
}

extern "C" void kernel_launch(void* const* d_in, const int* in_sizes, int n_in,
                              void* d_out, int out_size, void* d_ws, size_t ws_size,
                              hipStream_t stream) {
    const float* atomf = (const float*)d_in[0];
    const float* nbrf  = (const float*)d_in[1];
    const float* smask = (const float*)d_in[2];
    const float* amask = (const float*)d_in[3];
    const float* Wa    = (const float*)d_in[4];
    const float* ba    = (const float*)d_in[5];
    const float* Wn    = (const float*)d_in[6];
    const float* bnb   = (const float*)d_in[7];
    const float* wal   = (const float*)d_in[8];
    const float* bal   = (const float*)d_in[9];
    const float* gam   = (const float*)d_in[10];
    const float* bet   = (const float*)d_in[11];
    float* outp = (float*)d_out;

    u16* B2 = (u16*)d_ws;   // 288 tiles * 1KB = 294912 B

    build_b2<<<72, 256, 0, stream>>>(Wn, Wa, B2);
    fused_all<<<BN_TOT / ATB, 256, 0, stream>>>(atomf, nbrf, smask, amask, ba,
                                                B2, bnb, wal, bal, gam, bet, outp);
}